// Round 7
// baseline (431.485 us; speedup 1.0000x reference)
//
#include <hip/hip_runtime.h>
#include <hip/hip_bf16.h>
#include <math.h>

// Problem constants
#define GQA_B   2
#define GQA_T   2048
#define GQA_E   2048      // embed dim
#define GQA_HQ  32        // query heads
#define GQA_HKV 8         // kv heads
#define GQA_HD  64        // head dim
#define GQA_EKV 1024      // 2*HKV*HD
#define GQA_M   (GQA_B * GQA_T)   // 4096 rows

typedef short  bf16x8 __attribute__((ext_vector_type(8)));
typedef float  f32x4  __attribute__((ext_vector_type(4)));

// async global->LDS, 16B per lane; LDS dest = wave-uniform base + lane*16
#define GLDS16(gsrc, ldst)                                                 \
  __builtin_amdgcn_global_load_lds(                                       \
      (const __attribute__((address_space(1))) void*)(gsrc),              \
      (__attribute__((address_space(3))) void*)(ldst), 16, 0, 0)

// fp32 -> bf16 round-to-nearest-even (bit trick)
__device__ __forceinline__ ushort f2b(float f) {
  union { float f; unsigned u; } c; c.f = f;
  unsigned u = c.u;
  u += 0x7fffu + ((u >> 16) & 1u);
  return (ushort)(u >> 16);
}

// ---------------------------------------------------------------------------
// fp32 -> bf16 conversion, vectorized, grid-stride
// ---------------------------------------------------------------------------
__global__ __launch_bounds__(256) void cvt_f32_bf16(
    const float* __restrict__ src, ushort* __restrict__ dst, int n4) {
  int i = blockIdx.x * blockDim.x + threadIdx.x;
  const int stride = gridDim.x * blockDim.x;
  for (; i < n4; i += stride) {
    float4 v = *(const float4*)(src + (size_t)i * 4);
    ushort4 o;
    o.x = f2b(v.x); o.y = f2b(v.y); o.z = f2b(v.z); o.w = f2b(v.w);
    *(ushort4*)(dst + (size_t)i * 4) = o;
  }
}

// ---------------------------------------------------------------------------
// bf16 MFMA GEMM (NT): C(M,N) = A(M,K) @ B(N,K)^T. 128x128 tile, BK=32,
// 256 threads (4 waves, 2x2 of 64x64). DOUBLE-BUFFERED linear LDS staged via
// global_load_lds width=16; stage buf^1 first, compute buf, ONE barrier/step.
// (unchanged from round 6 — verified)
// ---------------------------------------------------------------------------
__device__ __forceinline__ void store_out(ushort* p, float v) { *p = f2b(v); }
__device__ __forceinline__ void store_out(float* p, float v)  { *p = v; }

template <typename CT>
__global__ __launch_bounds__(256) void gemm_nt_bf16(
    const ushort* __restrict__ A, const ushort* __restrict__ B,
    CT* __restrict__ C, int M, int N, int K) {
  __shared__ __align__(16) ushort As[2 * 128 * 32];   // 16KB
  __shared__ __align__(16) ushort Bs[2 * 128 * 32];   // 16KB
  const int tid = threadIdx.x;
  const int l  = tid & 63;
  const int w  = tid >> 6;
  const int lm = l & 15;
  const int lg = l >> 4;
  const int wm = w & 1;
  const int wn = w >> 1;
  const int bm = blockIdx.y * 128;
  const int bn = blockIdx.x * 128;

  const int srow = w * 32 + (l >> 2);
  const int scol = (l & 3) * 8;
  const ushort* Ag = A + (size_t)(bm + srow) * K + scol;
  const ushort* Bg = B + (size_t)(bn + srow) * K + scol;
  char* ldsAw = (char*)As + w * 2048;
  char* ldsBw = (char*)Bs + w * 2048;

  f32x4 acc[4][4];
#pragma unroll
  for (int i = 0; i < 4; ++i)
#pragma unroll
    for (int j = 0; j < 4; ++j)
#pragma unroll
      for (int r = 0; r < 4; ++r) acc[i][j][r] = 0.f;

  const int nk = K >> 5;
  GLDS16(Ag,                  ldsAw);
  GLDS16(Ag + (size_t)16 * K, ldsAw + 1024);
  GLDS16(Bg,                  ldsBw);
  GLDS16(Bg + (size_t)16 * K, ldsBw + 1024);
  __syncthreads();

  int cur = 0;
  for (int ks = 0; ks < nk; ++ks) {
    if (ks + 1 < nk) {
      const size_t k0 = (size_t)(ks + 1) * 32;
      char* la = ldsAw + (cur ^ 1) * 8192;
      char* lb = ldsBw + (cur ^ 1) * 8192;
      GLDS16(Ag + k0,                  la);
      GLDS16(Ag + (size_t)16 * K + k0, la + 1024);
      GLDS16(Bg + k0,                  lb);
      GLDS16(Bg + (size_t)16 * K + k0, lb + 1024);
    }
    const ushort* Ac = As + cur * 4096;
    const ushort* Bc = Bs + cur * 4096;
    bf16x8 af[4], bfr[4];
#pragma unroll
    for (int mf = 0; mf < 4; ++mf)
      af[mf] = *(const bf16x8*)(Ac + (wm * 64 + mf * 16 + lm) * 32 + lg * 8);
#pragma unroll
    for (int nf = 0; nf < 4; ++nf)
      bfr[nf] = *(const bf16x8*)(Bc + (wn * 64 + nf * 16 + lm) * 32 + lg * 8);
#pragma unroll
    for (int mf = 0; mf < 4; ++mf)
#pragma unroll
      for (int nf = 0; nf < 4; ++nf)
        acc[mf][nf] = __builtin_amdgcn_mfma_f32_16x16x32_bf16(
            af[mf], bfr[nf], acc[mf][nf], 0, 0, 0);
    __syncthreads();
    cur ^= 1;
  }

#pragma unroll
  for (int mf = 0; mf < 4; ++mf)
#pragma unroll
    for (int nf = 0; nf < 4; ++nf)
#pragma unroll
      for (int r = 0; r < 4; ++r) {
        const int row = bm + wm * 64 + mf * 16 + lg * 4 + r;
        const int col = bn + wn * 64 + nf * 16 + lm;
        store_out(C + (size_t)row * N + col, acc[mf][nf][r]);
      }
}

// ---------------------------------------------------------------------------
// Causal GQA flash attention, bf16 MFMA, swapped QK^T (lane owns one q-row
// per fragment), QBLK=128 (4 waves x 32 q-rows: 2 q-frags/wave share K/V
// frags -> 32 MFMA per wave-tile vs 16), KVBLK=64, LPT, double-buffered
// K (GLDS, pre-swizzled source) + V (reg transpose, issue-early/write-late),
// defer-max rescale (T13, exact), setprio around MFMA clusters (T5).
// ---------------------------------------------------------------------------
__global__ __launch_bounds__(256) void gqa_attn_mfma(
    const ushort* __restrict__ Q, const ushort* __restrict__ KV,
    ushort* __restrict__ Oat) {
  const int T = GQA_T, EQ = GQA_E, EKV = GQA_EKV;
  const int qt  = (int)gridDim.x - 1 - (int)blockIdx.x;  // longest first
  const int qt0 = qt * 128;
  const int hq  = blockIdx.y;
  const int b   = blockIdx.z;
  const int hkv = hq >> 2;

  __shared__ __align__(16) ushort Ks[2 * 64 * 64];   // 16KB [buf][key][d] swz
  __shared__ __align__(16) ushort Vt[2 * 64 * 64];   // 16KB [buf][d][key] swz
  __shared__ __align__(16) ushort Ps[4 * 32 * 64];   // 16KB per-wave [q'][key] swz

  const int tid = threadIdx.x;
  const int w  = tid >> 6;
  const int l  = tid & 63;
  const int lm = l & 15;
  const int lg = l >> 4;

  // Q B-fragments: frag fq rows q = qt0 + w*32 + fq*16 + lm
  const size_t qr0 = ((size_t)b * T + qt0 + 32 * w + lm) * EQ + hq * 64;
  bf16x8 qa[2][2];
  qa[0][0] = *(const bf16x8*)(Q + qr0 + lg * 8);
  qa[0][1] = *(const bf16x8*)(Q + qr0 + 32 + lg * 8);
  qa[1][0] = *(const bf16x8*)(Q + qr0 + (size_t)16 * EQ + lg * 8);
  qa[1][1] = *(const bf16x8*)(Q + qr0 + (size_t)16 * EQ + 32 + lg * 8);

  f32x4 oacc[2][4];
#pragma unroll
  for (int fq = 0; fq < 2; ++fq)
#pragma unroll
    for (int nd = 0; nd < 4; ++nd)
#pragma unroll
      for (int r = 0; r < 4; ++r) oacc[fq][nd][r] = 0.f;
  float m2[2]  = {-INFINITY, -INFINITY};
  float lsum[2] = {0.f, 0.f};
  const float SCL2 = 0.125f * 1.44269504088896f;   // scale * log2(e)
  const float THR2 = 11.5f;                        // defer-max threshold (log2)

  const size_t kvbase = (size_t)b * T * EKV + hkv * 64;

  // K staging map (pre-swizzled source, rule #21)
  const int k_key  = w * 8 + (l >> 3);
  const int k_srcd = (((l & 7) ^ (l >> 3)) * 8);
  char* PsB = (char*)Ps + w * 4096;                // 32 rows x 128B per wave
  const int pswz = (lm & 7) << 4;
  const size_t vgbase = kvbase + 512 + (size_t)l * EKV + w * 8;

  const int nt = 2 * qt + 2;

  // ---- prologue: stage tile 0 into buffer 0 ----
  {
    const ushort* kg = KV + kvbase + (size_t)k_key * EKV + k_srcd;
    GLDS16(kg,                    (char*)Ks + w * 1024);
    GLDS16(kg + (size_t)32 * EKV, (char*)Ks + (4 + w) * 1024);
    int4 v0 = *(const int4*)(KV + vgbase);
    int4 v1 = *(const int4*)(KV + vgbase + 32);
    union { int4 v; ushort u[8]; } a, bq;
    a.v = v0; bq.v = v1;
#pragma unroll
    for (int j = 0; j < 8; ++j) {
      const int d0 = w * 8 + j;
      *(ushort*)((char*)Vt + d0 * 128 + ((2 * l) ^ ((d0 & 7) << 4))) = a.u[j];
      const int d1 = 32 + w * 8 + j;
      *(ushort*)((char*)Vt + d1 * 128 + ((2 * l) ^ ((d1 & 7) << 4))) = bq.u[j];
    }
  }
  __syncthreads();

  int cur = 0;
  for (int t = 0; t < nt; ++t) {
    const int s0 = t * 64;
    const bool pf = (t + 1 < nt);
    int4 nv0, nv1;
    if (pf) {   // issue next tile's loads first
      const size_t s1 = (size_t)(t + 1) * 64;
      nv0 = *(const int4*)(KV + vgbase + s1 * EKV);
      nv1 = *(const int4*)(KV + vgbase + s1 * EKV + 32);
      const ushort* kg = KV + kvbase + (s1 + k_key) * EKV + k_srcd;
      char* kb = (char*)Ks + (cur ^ 1) * 8192;
      GLDS16(kg,                    kb + w * 1024);
      GLDS16(kg + (size_t)32 * EKV, kb + (4 + w) * 1024);
    }
    const char* KsB = (const char*)Ks + cur * 8192;
    const char* VtB = (const char*)Vt + cur * 8192;

    // ---- S^T = K Q^T for both q-frags (K-frags shared) ----
    f32x4 sacc[2][4];
#pragma unroll
    for (int fq = 0; fq < 2; ++fq)
#pragma unroll
      for (int nf = 0; nf < 4; ++nf)
#pragma unroll
        for (int r = 0; r < 4; ++r) sacc[fq][nf][r] = 0.f;
    __builtin_amdgcn_s_setprio(1);
#pragma unroll
    for (int nf = 0; nf < 4; ++nf) {
      const int krow = nf * 16 + lm;
      const int swz = (krow & 7) << 4;
      bf16x8 kb0 = *(const bf16x8*)(KsB + krow * 128 + ((lg * 16) ^ swz));
      bf16x8 kb1 = *(const bf16x8*)(KsB + krow * 128 + ((64 + lg * 16) ^ swz));
#pragma unroll
      for (int fq = 0; fq < 2; ++fq) {
        sacc[fq][nf] = __builtin_amdgcn_mfma_f32_16x16x32_bf16(kb0, qa[fq][0], sacc[fq][nf], 0, 0, 0);
        sacc[fq][nf] = __builtin_amdgcn_mfma_f32_16x16x32_bf16(kb1, qa[fq][1], sacc[fq][nf], 0, 0, 0);
      }
    }
    __builtin_amdgcn_s_setprio(0);

    // ---- causal mask (only tiles crossing this wave's rows) ----
    const int qw0 = qt0 + 32 * w;
    if (s0 + 63 > qw0) {
#pragma unroll
      for (int fq = 0; fq < 2; ++fq) {
        const int qg = qw0 + fq * 16 + lm;
#pragma unroll
        for (int nf = 0; nf < 4; ++nf)
#pragma unroll
          for (int r = 0; r < 4; ++r) {
            const int sg = s0 + nf * 16 + lg * 4 + r;
            if (sg > qg) sacc[fq][nf][r] = -INFINITY;
          }
      }
    }

    // ---- online softmax with defer-max (T13): two independent row chains ----
    float mt[2];
#pragma unroll
    for (int fq = 0; fq < 2; ++fq) {
      float m = -INFINITY;
#pragma unroll
      for (int nf = 0; nf < 4; ++nf)
#pragma unroll
        for (int r = 0; r < 4; ++r) m = fmaxf(m, sacc[fq][nf][r]);
      m = fmaxf(m, __shfl_xor(m, 16));
      m = fmaxf(m, __shfl_xor(m, 32));
      mt[fq] = m * SCL2;
    }
    const bool small_ = (mt[0] <= m2[0] + THR2) && (mt[1] <= m2[1] + THR2);
    if (!__all(small_)) {   // rescale pass (rare after warm-up)
#pragma unroll
      for (int fq = 0; fq < 2; ++fq) {
        const float mn = fmaxf(m2[fq], mt[fq]);
        const float al = exp2f(m2[fq] - mn);   // first tile: exp2(-inf)=0
        m2[fq] = mn;
        lsum[fq] *= al;
        float ar[4];
#pragma unroll
        for (int r = 0; r < 4; ++r) ar[r] = __shfl(al, lg * 4 + r);
#pragma unroll
        for (int nd = 0; nd < 4; ++nd)
#pragma unroll
          for (int r = 0; r < 4; ++r) oacc[fq][nd][r] *= ar[r];
      }
    }
#pragma unroll
    for (int fq = 0; fq < 2; ++fq) {
      float ssum = 0.f;
#pragma unroll
      for (int nf = 0; nf < 4; ++nf)
#pragma unroll
        for (int r = 0; r < 4; ++r) {
          const float p = exp2f(fmaf(sacc[fq][nf][r], SCL2, -m2[fq]));
          sacc[fq][nf][r] = p;
          ssum += p;
        }
      ssum += __shfl_xor(ssum, 16);
      ssum += __shfl_xor(ssum, 32);
      lsum[fq] += ssum;
    }

    // ---- P -> per-wave LDS (row' = fq*16+lm), b64 packed writes ----
#pragma unroll
    for (int fq = 0; fq < 2; ++fq)
#pragma unroll
      for (int nf = 0; nf < 4; ++nf) {
        union { uint2 v; __hip_bfloat162 h[2]; } pk;
        pk.h[0] = __float22bfloat162_rn(make_float2(sacc[fq][nf][0], sacc[fq][nf][1]));
        pk.h[1] = __float22bfloat162_rn(make_float2(sacc[fq][nf][2], sacc[fq][nf][3]));
        *(uint2*)(PsB + fq * 2048 + lm * 128 + ((nf * 32 + lg * 8) ^ pswz)) = pk.v;
      }

    // ---- O += P V (V-frags shared across fq) ----
    {
      bf16x8 pa[2][2];
#pragma unroll
      for (int fq = 0; fq < 2; ++fq) {
        pa[fq][0] = *(const bf16x8*)(PsB + fq * 2048 + lm * 128 + ((lg * 16) ^ pswz));
        pa[fq][1] = *(const bf16x8*)(PsB + fq * 2048 + lm * 128 + ((64 + lg * 16) ^ pswz));
      }
      __builtin_amdgcn_s_setprio(1);
#pragma unroll
      for (int nd = 0; nd < 4; ++nd) {
        const int vrow = nd * 16 + lm;
        const int vswz = (vrow & 7) << 4;
        bf16x8 vb0 = *(const bf16x8*)(VtB + vrow * 128 + ((lg * 16) ^ vswz));
        bf16x8 vb1 = *(const bf16x8*)(VtB + vrow * 128 + ((64 + lg * 16) ^ vswz));
#pragma unroll
        for (int fq = 0; fq < 2; ++fq) {
          oacc[fq][nd] = __builtin_amdgcn_mfma_f32_16x16x32_bf16(pa[fq][0], vb0, oacc[fq][nd], 0, 0, 0);
          oacc[fq][nd] = __builtin_amdgcn_mfma_f32_16x16x32_bf16(pa[fq][1], vb1, oacc[fq][nd], 0, 0, 0);
        }
      }
      __builtin_amdgcn_s_setprio(0);
    }

    // ---- write-late: next tile's V regs -> Vt[buf^1] ----
    if (pf) {
      char* vb = (char*)Vt + (cur ^ 1) * 8192;
      union { int4 v; ushort u[8]; } a, bq;
      a.v = nv0; bq.v = nv1;
#pragma unroll
      for (int j = 0; j < 8; ++j) {
        const int d0 = w * 8 + j;
        *(ushort*)(vb + d0 * 128 + ((2 * l) ^ ((d0 & 7) << 4))) = a.u[j];
        const int d1 = 32 + w * 8 + j;
        *(ushort*)(vb + d1 * 128 + ((2 * l) ^ ((d1 & 7) << 4))) = bq.u[j];
      }
    }
    __syncthreads();   // drains K prefetch (vmcnt 0) + V writes; buf reads done
    cur ^= 1;
  }

  // ---- epilogue: O / l, bf16 out ----
#pragma unroll
  for (int fq = 0; fq < 2; ++fq) {
    const float inv_own = 1.f / lsum[fq];
    float ir[4];
#pragma unroll
    for (int r = 0; r < 4; ++r) ir[r] = __shfl(inv_own, lg * 4 + r);
    const size_t ob = ((size_t)b * T + qt0 + 32 * w + fq * 16 + lg * 4) * EQ + hq * 64 + lm;
#pragma unroll
    for (int nd = 0; nd < 4; ++nd)
#pragma unroll
      for (int r = 0; r < 4; ++r)
        Oat[ob + (size_t)r * EQ + nd * 16] = f2b(oacc[fq][nd][r] * ir[r]);
  }
}

// ---------------------------------------------------------------------------
extern "C" void kernel_launch(void* const* d_in, const int* in_sizes, int n_in,
                              void* d_out, int out_size, void* d_ws, size_t ws_size,
                              hipStream_t stream) {
  const float* x   = (const float*)d_in[0];   // (B,T,E)
  const float* Wq  = (const float*)d_in[1];   // (E,E)
  const float* Wkv = (const float*)d_in[2];   // (1024,E)
  const float* Wo  = (const float*)d_in[3];   // (E,E)
  float* out = (float*)d_out;                  // (B,T,E) fp32

  // bf16 workspace layout (ushort elements); total ~76 MB
  ushort* xb   = (ushort*)d_ws;
  ushort* wqb  = xb   + (size_t)GQA_M * GQA_E;
  ushort* wkvb = wqb  + (size_t)GQA_E * GQA_E;
  ushort* wob  = wkvb + (size_t)GQA_EKV * GQA_E;
  ushort* qb   = wob  + (size_t)GQA_E * GQA_E;
  ushort* kvb  = qb   + (size_t)GQA_M * GQA_E;
  ushort* attb = kvb  + (size_t)GQA_M * GQA_EKV;

  cvt_f32_bf16<<<2048, 256, 0, stream>>>(x,   xb,   GQA_M * GQA_E / 4);
  cvt_f32_bf16<<<1024, 256, 0, stream>>>(Wq,  wqb,  GQA_E * GQA_E / 4);
  cvt_f32_bf16<<<512,  256, 0, stream>>>(Wkv, wkvb, GQA_EKV * GQA_E / 4);
  cvt_f32_bf16<<<1024, 256, 0, stream>>>(Wo,  wob,  GQA_E * GQA_E / 4);

  gemm_nt_bf16<ushort><<<dim3(GQA_E / 128, GQA_M / 128), 256, 0, stream>>>(
      xb, wqb, qb, GQA_M, GQA_E, GQA_E);
  gemm_nt_bf16<ushort><<<dim3(GQA_EKV / 128, GQA_M / 128), 256, 0, stream>>>(
      xb, wkvb, kvb, GQA_M, GQA_EKV, GQA_E);
  gqa_attn_mfma<<<dim3(GQA_T / 128, GQA_HQ, GQA_B), 256, 0, stream>>>(
      qb, kvb, attb);
  gemm_nt_bf16<float><<<dim3(GQA_E / 128, GQA_M / 128), 256, 0, stream>>>(
      attb, wob, out, GQA_M, GQA_E, GQA_E);
}